// Round 4
// baseline (316.973 us; speedup 1.0000x reference)
//
#include <hip/hip_runtime.h>
#include <hip/hip_bf16.h>
#include <math.h>

// Problem constants
#define B_      4
#define S_      512
#define H_      768
#define NH_     4
#define DH_     192
#define N_      4096          // spans per batch
#define WD_     64
#define INNER_  3072
#define INDIM_  1600
#define SP1     513           // S+1 (CLS prepended)
#define ROWS_X  (B_*SP1)      // 2052
#define ROWS_XP 2176          // padded to multiple of 128
#define NSPAN   (B_*N_)       // 16384

typedef __attribute__((ext_vector_type(8))) short bf16x8;
typedef __attribute__((ext_vector_type(4))) float f32x4;
typedef __attribute__((ext_vector_type(16))) float f32x16;

__device__ __forceinline__ unsigned short f2bf(float f){
    unsigned u = __builtin_bit_cast(unsigned, f);
    u = u + 0x7FFFu + ((u >> 16) & 1u);   // round-to-nearest-even
    return (unsigned short)(u >> 16);
}

__device__ __forceinline__ float wave_sum(float p){
    #pragma unroll
    for (int off = 32; off > 0; off >>= 1) p += __shfl_down(p, off);
    return p;
}

// async global->LDS, 16B per lane. lds must be wave-uniform; g is per-lane.
__device__ __forceinline__ void gld16(unsigned short* lds, const unsigned short* g){
    __builtin_amdgcn_global_load_lds(
        (const __attribute__((address_space(1))) unsigned int*)(const void*)g,
        (__attribute__((address_space(3))) unsigned int*)(void*)lds,
        16, 0, 0);
}

__device__ __forceinline__ void wgbar(){
    asm volatile("" ::: "memory");
    __builtin_amdgcn_s_barrier();
    asm volatile("" ::: "memory");
}
#define VMW(n) asm volatile("s_waitcnt vmcnt(" #n ")" ::: "memory")

// ---------------------------------------------------------------------------
// 0. span_masks encoding detection
// ---------------------------------------------------------------------------
__global__ void detect_mask_kernel(const unsigned* __restrict__ masks, int* __restrict__ flag){
    __shared__ int s_any;
    if (threadIdx.x == 0) s_any = 0;
    __syncthreads();
    int any = 0;
    for (int i = threadIdx.x; i < 4096; i += 256){
        unsigned v = masks[i];
        if (!(v == 0u || v == 1u || v == 0x3F800000u)) any = 1;
    }
    if (any) s_any = 1;
    __syncthreads();
    if (threadIdx.x == 0) *flag = s_any;
}

// ---------------------------------------------------------------------------
// 1. f32 -> bf16 conversions
// ---------------------------------------------------------------------------
__global__ void conv_f32_bf16(const float* __restrict__ in, unsigned short* __restrict__ out, long n4){
    long i = (long)blockIdx.x * blockDim.x + threadIdx.x;
    long stride = (long)gridDim.x * blockDim.x;
    for (; i < n4; i += stride){
        float4 v = ((const float4*)in)[i];
        ushort4 o;
        o.x = f2bf(v.x); o.y = f2bf(v.y); o.z = f2bf(v.z); o.w = f2bf(v.w);
        ((ushort4*)out)[i] = o;
    }
}

__global__ void conv_w1a_kernel(const float* __restrict__ w1, unsigned short* __restrict__ out){
    int i = blockIdx.x;
    int k4 = threadIdx.x;
    if (k4 < 192){
        float4 v = ((const float4*)&w1[(long)i * INDIM_])[k4];
        ushort4 o; o.x = f2bf(v.x); o.y = f2bf(v.y); o.z = f2bf(v.z); o.w = f2bf(v.w);
        ((ushort4*)&out[(long)i * 768])[k4] = o;
    }
}

__global__ void transconv_kernel(const float* __restrict__ in, unsigned short* __restrict__ out){
    __shared__ float tile[32][33];
    int bx = blockIdx.x * 32, by = blockIdx.y * 32;
    int tx = threadIdx.x & 31, ty = threadIdx.x >> 5;
    #pragma unroll
    for (int r = 0; r < 32; r += 8)
        tile[ty + r][tx] = in[(long)(by + ty + r) * 768 + bx + tx];
    __syncthreads();
    #pragma unroll
    for (int r = 0; r < 32; r += 8)
        out[(long)(bx + ty + r) * 768 + by + tx] = f2bf(tile[tx][ty + r]);
}

// ---------------------------------------------------------------------------
// 2. X = [cls_embedding; token_reps], bf16
// ---------------------------------------------------------------------------
__global__ void build_x_kernel(const float* __restrict__ tok, const float* __restrict__ clsemb,
                               unsigned short* __restrict__ X){
    int r = blockIdx.x;
    int b = r / SP1, s = r % SP1;
    const float* src = (s == 0) ? clsemb : &tok[((long)b * S_ + (s - 1)) * H_];
    for (int d = threadIdx.x; d < H_; d += 256)
        X[(long)r * H_ + d] = f2bf(src[d]);
}

// ---------------------------------------------------------------------------
// 3. merged precompute: q (192 blk), BiasC (768 blk), WC (768 blk)
// ---------------------------------------------------------------------------
__global__ void precomp_kernel(const float* __restrict__ clsemb, const float* __restrict__ in_proj_w,
                               const float* __restrict__ in_proj_b, float* __restrict__ q,
                               const float* __restrict__ w1, const float* __restrict__ b1,
                               const float* __restrict__ opb, const float* __restrict__ cls_reps,
                               float* __restrict__ BiasC, const float* __restrict__ wtab,
                               float* __restrict__ WC){
    int blk = blockIdx.x;
    int wave = threadIdx.x >> 6, lane = threadIdx.x & 63;
    if (blk < 192){                                   // q projection
        int j = blk * 4 + wave;
        const float* wr = &in_proj_w[(long)j * H_];
        float p = 0.f;
        #pragma unroll
        for (int i = 0; i < 12; ++i) p += clsemb[lane + 64*i] * wr[lane + 64*i];
        p = wave_sum(p);
        if (lane == 0) q[j] = p + in_proj_b[j];
    } else if (blk < 192 + 768){                      // BiasC
        int i = (blk - 192) * 4 + wave;
        const float* row = &w1[(long)i * INDIM_];
        float p0 = 0.f, pb0 = 0.f, pb1 = 0.f, pb2 = 0.f, pb3 = 0.f;
        #pragma unroll
        for (int t = 0; t < 12; ++t){
            int k = lane + 64*t;
            p0 += opb[k] * row[k];
            float rv = row[832 + k];
            pb0 += cls_reps[0*H_ + k] * rv;
            pb1 += cls_reps[1*H_ + k] * rv;
            pb2 += cls_reps[2*H_ + k] * rv;
            pb3 += cls_reps[3*H_ + k] * rv;
        }
        p0 = wave_sum(p0); pb0 = wave_sum(pb0); pb1 = wave_sum(pb1);
        pb2 = wave_sum(pb2); pb3 = wave_sum(pb3);
        if (lane == 0){
            float base = b1[i] + p0;
            BiasC[0*INNER_ + i] = base + pb0;
            BiasC[1*INNER_ + i] = base + pb1;
            BiasC[2*INNER_ + i] = base + pb2;
            BiasC[3*INNER_ + i] = base + pb3;
        }
    } else {                                          // WC
        int i = (blk - 192 - 768) * 4 + wave;
        float rv = w1[(long)i * INDIM_ + 768 + lane];
        #pragma unroll
        for (int w = 0; w < 9; ++w){
            float p = wave_sum(wtab[w * WD_ + lane] * rv);
            if (lane == 0) WC[w * INNER_ + i] = p;
        }
    }
}

// ---------------------------------------------------------------------------
// 5. base scores
// ---------------------------------------------------------------------------
__global__ void scores_kernel(const float* __restrict__ q, const float* __restrict__ KV,
                              float* __restrict__ SC){
    int r = blockIdx.x;
    int h = threadIdx.x >> 6, lane = threadIdx.x & 63;
    const float* krow = &KV[(long)r * 1536 + h * DH_];
    const float* qh   = &q[h * DH_];
    float p = 0.f;
    #pragma unroll
    for (int i = 0; i < 3; ++i) p += qh[lane + 64*i] * krow[lane + 64*i];
    p = wave_sum(p);
    if (lane == 0){
        const float scale = 0.0721687836487032f;
        SC[((r / SP1) * NH_ + h) * SP1 + (r % SP1)] = p * scale;
    }
}

// ---------------------------------------------------------------------------
// 6. per-span attention -> CTX bf16
// ---------------------------------------------------------------------------
__global__ __launch_bounds__(256) void attn_kernel(
    const int* __restrict__ span_ids, const void* __restrict__ masks,
    const int* __restrict__ flag, const float* __restrict__ SC,
    const float* __restrict__ KV, unsigned short* __restrict__ CTX)
{
    int blk = blockIdx.x;
    int b = blk >> 12, n = blk & (N_ - 1);
    int t = threadIdx.x;
    __shared__ float w_sh[NH_][9];
    __shared__ int info[2];

    if (t == 0){
        long idx = (long)b * N_ + n;
        int start = span_ids[idx * 2 + 0];
        int end   = span_ids[idx * 2 + 1];
        bool sm = (*flag == 0) ? (((const unsigned*)masks)[idx] != 0u)
                               : (((const unsigned char*)masks)[idx] != 0);
        int cnt = sm ? (end - start) : 0;
        if (cnt < 0) cnt = 0;
        if (cnt > 8) cnt = 8;
        if (start < 0) start = 0;
        if (start + cnt > S_) cnt = S_ - start;
        info[0] = start; info[1] = cnt;
    }
    __syncthreads();
    int start = info[0], cnt = info[1];

    if (t < NH_){
        int h = t;
        const float* sc = &SC[((long)b * NH_ + h) * SP1];
        float m = sc[0];
        for (int j = 0; j < cnt; ++j) m = fmaxf(m, sc[1 + start + j]);
        float e0 = expf(sc[0] - m), sum = e0;
        float ej[8];
        for (int j = 0; j < cnt; ++j){ ej[j] = expf(sc[1 + start + j] - m); sum += ej[j]; }
        float inv = 1.f / sum;
        w_sh[h][0] = e0 * inv;
        for (int j = 0; j < cnt; ++j) w_sh[h][1 + j] = ej[j] * inv;
    }
    __syncthreads();

    long ctxbase = ((long)b * N_ + n) * H_;
    const float* V = &KV[(long)(b * SP1) * 1536 + H_];
    #pragma unroll
    for (int i = 0; i < 3; ++i){
        int d = t + 256 * i;
        int h = d / DH_;
        float a = w_sh[h][0] * V[d];
        for (int j = 0; j < cnt; ++j)
            a += w_sh[h][1 + j] * V[(long)(1 + start + j) * 1536 + d];
        CTX[ctxbase + d] = f2bf(a);
    }
}

// ---------------------------------------------------------------------------
// 7a. m97 128x128 GEMM (proven) — small GEMMs (KV, Wfuse)
// ---------------------------------------------------------------------------
template<int EPI>
__global__ __launch_bounds__(256, 2) void gemm97(
    const unsigned short* __restrict__ A, const unsigned short* __restrict__ Bm,
    const float* __restrict__ biasA, void* __restrict__ Cp,
    int M, int N, int K, int lda, int ldb, int ldc, int nbx)
{
    __shared__ unsigned short As[128 * 32];
    __shared__ unsigned short Bs[128 * 32];
    const int t = threadIdx.x, lane = t & 63, wave = t >> 6;
    const int wr = wave >> 1, wcid = wave & 1;

    int nwg = gridDim.x;
    int bid = blockIdx.x;
    int swz = ((nwg & 7) == 0) ? ((bid & 7) * (nwg >> 3) + (bid >> 3)) : bid;
    const int m0 = (swz / nbx) * 128;
    const int n0 = (swz % nbx) * 128;

    f32x4 acc[4][4];
    #pragma unroll
    for (int i = 0; i < 4; ++i)
        #pragma unroll
        for (int j = 0; j < 4; ++j)
            acc[i][j] = (f32x4){0.f, 0.f, 0.f, 0.f};

    const unsigned short* gA = A + (long)(m0 + wave*32 + (lane >> 2)) * lda + (lane & 3) * 8;
    const unsigned short* gB = Bm + (long)(n0 + wave*32 + (lane >> 2)) * ldb + (lane & 3) * 8;
    unsigned short* lA = &As[wave * 32 * 32];
    unsigned short* lB = &Bs[wave * 32 * 32];
    const long a16 = (long)16 * lda, b16 = (long)16 * ldb;

    for (int k0 = 0; k0 < K; k0 += 32){
        gld16(lA,       gA + k0);
        gld16(lA + 512, gA + a16 + k0);
        gld16(lB,       gB + k0);
        gld16(lB + 512, gB + b16 + k0);
        __syncthreads();

        bf16x8 af[4], bfr[4];
        #pragma unroll
        for (int f = 0; f < 4; ++f){
            af[f]  = *(const bf16x8*)&As[(wr*64 + f*16 + (lane & 15)) * 32 + (lane >> 4) * 8];
            bfr[f] = *(const bf16x8*)&Bs[(wcid*64 + f*16 + (lane & 15)) * 32 + (lane >> 4) * 8];
        }
        #pragma unroll
        for (int i = 0; i < 4; ++i)
            #pragma unroll
            for (int j = 0; j < 4; ++j)
                acc[i][j] = __builtin_amdgcn_mfma_f32_16x16x32_bf16(af[i], bfr[j], acc[i][j], 0, 0, 0);
        __syncthreads();
    }

    const int r0 = (lane >> 4) * 4;
    const int cc = lane & 15;
    #pragma unroll
    for (int i = 0; i < 4; ++i){
        int rowb = m0 + wr*64 + i*16 + r0;
        #pragma unroll
        for (int j = 0; j < 4; ++j){
            int col = n0 + wcid*64 + j*16 + cc;
            float cb = biasA ? biasA[col] : 0.f;
            #pragma unroll
            for (int r = 0; r < 4; ++r){
                long o = (long)(rowb + r) * ldc + col;
                float v = acc[i][j][r] + cb;
                if (EPI == 1) ((unsigned short*)Cp)[o] = f2bf(v);
                else          ((float*)Cp)[o] = v;
            }
        }
    }
}

// ---------------------------------------------------------------------------
// 7b. 256x256 GEMM v2: 32x32x16 MFMA, 3 phases/K-tile, 1 barrier/phase,
//     counted vmcnt (never 0 mid-loop), T2 XOR-swizzle, T5 setprio.
//     C(MxN) = A(MxK) @ B(NxK)^T.  M%256==0, N%256==0, K%64==0, K>=128.
//     8 waves (2M x 4N), per-wave 128x64 out, BK=64, LDS 128KB dbuf.
//     Units/K-tile (2 gld16 each): U1=A-mq0 rows{0-63,128-191} (read P1),
//     U2=B-even 32-col-blocks (P1), U3=B-odd (P2), U4=A-mq1 (P3).
//     Steady FIFO per wave: P1 stage U1', VMW(4)->drain U3; P2 stage U2',
//     VMW(4)->U4; P3 stage U3'U4', VMW(4)->U1'U2'. Tail: VMW(2)/VMW(0).
//     EPI: 0 = f32 out + col bias; 2 = bf16 out + relu + BiasC[4][N] + WC[9][N]
// ---------------------------------------------------------------------------
template<int EPI, int LDA_, int LDB_>
__global__ __launch_bounds__(512, 2) void gemm256v2(
    const unsigned short* __restrict__ A, const unsigned short* __restrict__ Bm,
    const float* __restrict__ biasA, const float* __restrict__ biasB,
    const int* __restrict__ widths, void* __restrict__ Cp,
    int K, int ldc, int nbx)
{
    __shared__ __align__(16) unsigned char lds[131072];
    const int t = threadIdx.x, lane = t & 63;
    const int wave = t >> 6;
    const int wr = wave >> 2, wc = wave & 3;      // 2M x 4N waves

    int nwg = gridDim.x, bid = blockIdx.x;
    int swz = ((nwg & 7) == 0) ? ((bid & 7) * (nwg >> 3) + (bid >> 3)) : bid;
    const int m0 = (swz / nbx) * 256;
    const int n0 = (swz % nbx) * 256;

    // ---- staging (source pre-swizzled; LDS dest linear, wave-private 1KB slices)
    const int rQ = t >> 3;                                  // 0..63
    const int cswz = ((t & 7) ^ (rQ & 7)) << 3;             // elements
    const unsigned short* sA = A + (long)(m0 + rQ) * LDA_ + cswz;
    const unsigned short* sB = Bm + (long)(n0 + ((rQ >> 5) * 64 + (rQ & 31))) * LDB_ + cswz;
    const int wsl = wave * 1024;

    // ---- ds_read bases (32x32 fragments) ----
    const int l31 = lane & 31;
    const int hi  = lane >> 5;
    const int kx  = hi * 16;                 // byte offset of k-half within 32B kstep
    const int key = (lane & 7) << 4;         // == (row&7)<<4 since row = l31 within 32-row frag
    const int aB  = wr * 8192 + l31 * 128;   // + mq*16384 + fi*4096
    const int bB  = wc * 4096 + l31 * 128;   // + an*16384

    f32x16 acc[4][2];
    #pragma unroll
    for (int i = 0; i < 4; ++i)
        #pragma unroll
        for (int j = 0; j < 2; ++j)
            #pragma unroll
            for (int e = 0; e < 16; ++e)
                acc[i][j][e] = 0.f;

    const int KT = K >> 6;

#define STG_(off, src) gld16((unsigned short*)(void*)(lds + (off) + wsl), (src))

    // ---- prologue: stage K-tile 0 into buf0, FIFO order U1..U4 ----
    STG_(0,             sA);
    STG_(8192,          sA + 128 * LDA_);
    STG_(65536,         sB);
    STG_(65536 + 8192,  sB + 128 * LDB_);
    STG_(65536 + 16384, sB + 32 * LDB_);
    STG_(65536 + 24576, sB + 160 * LDB_);
    STG_(16384,         sA + 64 * LDA_);
    STG_(24576,         sA + 192 * LDA_);
    VMW(4);
    wgbar();

    for (int kt = 0; kt < KT; ++kt){
        const unsigned rA = (unsigned)(kt & 1) * 32768u;
        const unsigned rB = 65536u + rA;
        const unsigned wA = (unsigned)((kt + 1) & 1) * 32768u;
        const unsigned wB = 65536u + wA;
        const unsigned short* pA = sA + (long)(kt + 1) * 64;
        const unsigned short* pB = sB + (long)(kt + 1) * 64;
        const bool more = (kt + 1 < KT);

        bf16x8 a[2][4], bE[4], bO[4];

        // ========== P1: read A-mq0 + B-even; MFMA acc[0..1][0] ==========
        #pragma unroll
        for (int fi = 0; fi < 2; ++fi)
            #pragma unroll
            for (int s = 0; s < 4; ++s)
                a[fi][s] = *(const bf16x8*)(lds + rA + aB + fi*4096 + ((s*32 + kx) ^ key));
        #pragma unroll
        for (int s = 0; s < 4; ++s)
            bE[s] = *(const bf16x8*)(lds + rB + bB + ((s*32 + kx) ^ key));
        if (more){ STG_(wA, pA); STG_(wA + 8192, pA + 128 * LDA_); }
        if (more){ VMW(4); } else { VMW(2); }
        wgbar();
        __builtin_amdgcn_s_setprio(1);
        #pragma unroll
        for (int fi = 0; fi < 2; ++fi)
            #pragma unroll
            for (int s = 0; s < 4; ++s)
                acc[fi][0] = __builtin_amdgcn_mfma_f32_32x32x16_bf16(a[fi][s], bE[s], acc[fi][0], 0, 0, 0);
        __builtin_amdgcn_s_setprio(0);

        // ========== P2: read B-odd; MFMA acc[0..1][1] ==========
        #pragma unroll
        for (int s = 0; s < 4; ++s)
            bO[s] = *(const bf16x8*)(lds + rB + 16384 + bB + ((s*32 + kx) ^ key));
        if (more){ STG_(wB, pB); STG_(wB + 8192, pB + 128 * LDB_); }
        if (more){ VMW(4); } else { VMW(0); }
        wgbar();
        __builtin_amdgcn_s_setprio(1);
        #pragma unroll
        for (int fi = 0; fi < 2; ++fi)
            #pragma unroll
            for (int s = 0; s < 4; ++s)
                acc[fi][1] = __builtin_amdgcn_mfma_f32_32x32x16_bf16(a[fi][s], bO[s], acc[fi][1], 0, 0, 0);
        __builtin_amdgcn_s_setprio(0);

        // ========== P3: read A-mq1; MFMA acc[2..3][0..1] ==========
        #pragma unroll
        for (int fi = 0; fi < 2; ++fi)
            #pragma unroll
            for (int s = 0; s < 4; ++s)
                a[fi][s] = *(const bf16x8*)(lds + rA + 16384 + aB + fi*4096 + ((s*32 + kx) ^ key));
        if (more){
            STG_(wB + 16384, pB + 32 * LDB_);  STG_(wB + 24576, pB + 160 * LDB_);
            STG_(wA + 16384, pA + 64 * LDA_);  STG_(wA + 24576, pA + 192 * LDA_);
            VMW(4);
        }
        wgbar();
        __builtin_amdgcn_s_setprio(1);
        #pragma unroll
        for (int fi = 0; fi < 2; ++fi)
            #pragma unroll
            for (int s = 0; s < 4; ++s){
                acc[2+fi][0] = __builtin_amdgcn_mfma_f32_32x32x16_bf16(a[fi][s], bE[s], acc[2+fi][0], 0, 0, 0);
                acc[2+fi][1] = __builtin_amdgcn_mfma_f32_32x32x16_bf16(a[fi][s], bO[s], acc[2+fi][1], 0, 0, 0);
            }
        __builtin_amdgcn_s_setprio(0);
        if (more) wgbar();
    }
#undef STG_

    // ---- epilogue: 32x32 C/D layout: col = lane&31, row = (r&3)+8*(r>>2)+4*hi
    const int Nn = nbx * 256;
    const float* bc = (EPI == 2) ? (biasA + (long)(m0 >> 12) * Nn) : nullptr;
    #pragma unroll
    for (int am = 0; am < 4; ++am){
        const int rowb = m0 + wr*128 + (am >> 1)*64 + (am & 1)*32 + hi*4;
        #pragma unroll
        for (int an = 0; an < 2; ++an){
            const int col = n0 + wc*64 + an*32 + l31;
            float cb = 0.f;
            if (EPI != 2 && biasA) cb = biasA[col];
            #pragma unroll
            for (int g = 0; g < 4; ++g){
                #pragma unroll
                for (int q = 0; q < 4; ++q){
                    int row = rowb + g*8 + q;
                    float v = acc[am][an][g*4 + q] + cb;
                    long o = (long)row * ldc + col;
                    if (EPI == 2){
                        int wv = widths[row];
                        wv = (wv < 0) ? 0 : ((wv > 8) ? 8 : wv);
                        v += bc[col] + biasB[(long)wv * Nn + col];
                        v = fmaxf(v, 0.f);
                        ((unsigned short*)Cp)[o] = f2bf(v);
                    } else {
                        ((float*)Cp)[o] = v;
                    }
                }
            }
        }
    }
}

// ---------------------------------------------------------------------------
extern "C" void kernel_launch(void* const* d_in, const int* in_sizes, int n_in,
                              void* d_out, int out_size, void* d_ws, size_t ws_size,
                              hipStream_t stream)
{
    const float* token_reps  = (const float*)d_in[0];
    const int*   span_ids    = (const int*)d_in[1];
    const void*  span_masks  = d_in[2];
    const float* cls_reps    = (const float*)d_in[3];
    const int*   span_widths = (const int*)d_in[4];
    const float* cls_emb     = (const float*)d_in[5];
    const float* in_proj_w   = (const float*)d_in[6];
    const float* in_proj_b   = (const float*)d_in[7];
    const float* out_proj_w  = (const float*)d_in[8];
    const float* out_proj_b  = (const float*)d_in[9];
    const float* width_table = (const float*)d_in[10];
    const float* w1          = (const float*)d_in[11];
    const float* b1          = (const float*)d_in[12];
    const float* w2          = (const float*)d_in[13];
    const float* b2          = (const float*)d_in[14];

    char* ws = (char*)d_ws;
    size_t off = 0;
    auto alloc = [&](size_t bytes)->char*{
        char* p = ws + off;
        off += (bytes + 255) & ~(size_t)255;
        return p;
    };
    int*            flag  = (int*)           alloc(4);
    float*          qbuf  = (float*)         alloc((size_t)H_ * 4);
    unsigned short* Xb    = (unsigned short*)alloc((size_t)ROWS_XP * H_ * 2);
    unsigned short* Wkv   = (unsigned short*)alloc((size_t)1536 * H_ * 2);
    float*          KV    = (float*)         alloc((size_t)ROWS_XP * 1536 * 4);
    float*          SC    = (float*)         alloc((size_t)B_ * NH_ * SP1 * 4);
    unsigned short* CTX   = (unsigned short*)alloc((size_t)NSPAN * H_ * 2);
    unsigned short* W1a   = (unsigned short*)alloc((size_t)INNER_ * H_ * 2);
    unsigned short* OutT  = (unsigned short*)alloc((size_t)H_ * H_ * 2);
    unsigned short* Wfuse = (unsigned short*)alloc((size_t)INNER_ * H_ * 2);
    unsigned short* W2b   = (unsigned short*)alloc((size_t)H_ * INNER_ * 2);
    unsigned short* H1    = (unsigned short*)alloc((size_t)NSPAN * INNER_ * 2);
    float*          BiasC = (float*)         alloc((size_t)B_ * INNER_ * 4);
    float*          WC    = (float*)         alloc((size_t)9 * INNER_ * 4);
    (void)ws_size; (void)in_sizes; (void)n_in; (void)out_size;

    // prep / conversions
    detect_mask_kernel<<<1, 256, 0, stream>>>((const unsigned*)span_masks, flag);
    build_x_kernel<<<ROWS_X, 256, 0, stream>>>(token_reps, cls_emb, Xb);
    conv_f32_bf16<<<512, 256, 0, stream>>>(in_proj_w + (size_t)768 * H_, Wkv, (long)(1536 * H_ / 4));
    conv_f32_bf16<<<512, 256, 0, stream>>>(w2, W2b, (long)(H_ * INNER_ / 4));
    conv_w1a_kernel<<<INNER_, 192, 0, stream>>>(w1, W1a);
    transconv_kernel<<<dim3(24, 24), 256, 0, stream>>>(out_proj_w, OutT);
    precomp_kernel<<<192 + 768 + 768, 256, 0, stream>>>(
        cls_emb, in_proj_w, in_proj_b, qbuf,
        w1, b1, out_proj_b, cls_reps, BiasC, width_table, WC);

    // Wfused = W1a @ OutT^T   (3072x768, K=768)
    gemm97<1><<<(768/128) * (INNER_/128), 256, 0, stream>>>(
        W1a, OutT, nullptr, Wfuse, INNER_, 768, 768, 768, 768, 768, 768/128);

    // KV = X @ [wk;wv]^T + b   (2176x1536, K=768)
    gemm97<0><<<(1536/128) * (ROWS_XP/128), 256, 0, stream>>>(
        Xb, Wkv, in_proj_b + 768, KV, ROWS_XP, 1536, 768, 768, 768, 1536, 1536/128);

    scores_kernel<<<ROWS_X, 256, 0, stream>>>(qbuf, KV, SC);
    attn_kernel<<<NSPAN, 256, 0, stream>>>(span_ids, span_masks, flag, SC, KV, CTX);

    // H1 = relu(CTX @ Wfused^T + BiasC[b] + WC[width])   (16384x3072, K=768)
    gemm256v2<2, 768, 768><<<(INNER_/256) * (NSPAN/256), 512, 0, stream>>>(
        CTX, Wfuse, BiasC, WC, span_widths, H1, 768, INNER_, INNER_/256);

    // out = H1 @ w2^T + b2   (16384x768, K=3072) -> f32 d_out
    gemm256v2<0, 3072, 3072><<<(768/256) * (NSPAN/256), 512, 0, stream>>>(
        H1, W2b, b2, nullptr, nullptr, (float*)d_out, 3072, 768, 768/256);
}

// Round 5
// 297.680 us; speedup vs baseline: 1.0648x; 1.0648x over previous
//
#include <hip/hip_runtime.h>
#include <hip/hip_bf16.h>
#include <math.h>

// Problem constants
#define B_      4
#define S_      512
#define H_      768
#define NH_     4
#define DH_     192
#define N_      4096          // spans per batch
#define WD_     64
#define INNER_  3072
#define INDIM_  1600
#define SP1     513           // S+1 (CLS prepended)
#define ROWS_X  (B_*SP1)      // 2052
#define ROWS_XP 2176          // padded to multiple of 128
#define NSPAN   (B_*N_)       // 16384

typedef __attribute__((ext_vector_type(8))) short bf16x8;
typedef __attribute__((ext_vector_type(4))) float f32x4;

__device__ __forceinline__ unsigned short f2bf(float f){
    unsigned u = __builtin_bit_cast(unsigned, f);
    u = u + 0x7FFFu + ((u >> 16) & 1u);   // round-to-nearest-even
    return (unsigned short)(u >> 16);
}
__device__ __forceinline__ float bf2f(unsigned hs){
    return __builtin_bit_cast(float, hs << 16);
}

__device__ __forceinline__ float wave_sum(float p){
    #pragma unroll
    for (int off = 32; off > 0; off >>= 1) p += __shfl_down(p, off);
    return p;
}

// async global->LDS, 16B per lane. lds must be wave-uniform; g is per-lane.
__device__ __forceinline__ void gld16(unsigned short* lds, const unsigned short* g){
    __builtin_amdgcn_global_load_lds(
        (const __attribute__((address_space(1))) unsigned int*)(const void*)g,
        (__attribute__((address_space(3))) unsigned int*)(void*)lds,
        16, 0, 0);
}

__device__ __forceinline__ void wgbar(){
    asm volatile("" ::: "memory");
    __builtin_amdgcn_s_barrier();
    asm volatile("" ::: "memory");
}
#define VMW(n) asm volatile("s_waitcnt vmcnt(" #n ")" ::: "memory")

// ---------------------------------------------------------------------------
// 0. span_masks encoding detection
// ---------------------------------------------------------------------------
__global__ void detect_mask_kernel(const unsigned* __restrict__ masks, int* __restrict__ flag){
    __shared__ int s_any;
    if (threadIdx.x == 0) s_any = 0;
    __syncthreads();
    int any = 0;
    for (int i = threadIdx.x; i < 4096; i += 256){
        unsigned v = masks[i];
        if (!(v == 0u || v == 1u || v == 0x3F800000u)) any = 1;
    }
    if (any) s_any = 1;
    __syncthreads();
    if (threadIdx.x == 0) *flag = s_any;
}

// ---------------------------------------------------------------------------
// 1. f32 -> bf16 conversions
// ---------------------------------------------------------------------------
__global__ void conv_f32_bf16(const float* __restrict__ in, unsigned short* __restrict__ out, long n4){
    long i = (long)blockIdx.x * blockDim.x + threadIdx.x;
    long stride = (long)gridDim.x * blockDim.x;
    for (; i < n4; i += stride){
        float4 v = ((const float4*)in)[i];
        ushort4 o;
        o.x = f2bf(v.x); o.y = f2bf(v.y); o.z = f2bf(v.z); o.w = f2bf(v.w);
        ((ushort4*)out)[i] = o;
    }
}

__global__ void conv_w1a_kernel(const float* __restrict__ w1, unsigned short* __restrict__ out){
    int i = blockIdx.x;
    int k4 = threadIdx.x;
    if (k4 < 192){
        float4 v = ((const float4*)&w1[(long)i * INDIM_])[k4];
        ushort4 o; o.x = f2bf(v.x); o.y = f2bf(v.y); o.z = f2bf(v.z); o.w = f2bf(v.w);
        ((ushort4*)&out[(long)i * 768])[k4] = o;
    }
}

__global__ void transconv_kernel(const float* __restrict__ in, unsigned short* __restrict__ out){
    __shared__ float tile[32][33];
    int bx = blockIdx.x * 32, by = blockIdx.y * 32;
    int tx = threadIdx.x & 31, ty = threadIdx.x >> 5;
    #pragma unroll
    for (int r = 0; r < 32; r += 8)
        tile[ty + r][tx] = in[(long)(by + ty + r) * 768 + bx + tx];
    __syncthreads();
    #pragma unroll
    for (int r = 0; r < 32; r += 8)
        out[(long)(bx + ty + r) * 768 + by + tx] = f2bf(tile[tx][ty + r]);
}

// V columns of KV -> bf16 VB (2052 x 768)
__global__ void vconv_kernel(const float* __restrict__ KV, unsigned short* __restrict__ VB){
    int r = blockIdx.x;
    int t = threadIdx.x;                 // 192 threads, float4 each
    float4 v = ((const float4*)&KV[(long)r * 1536 + 768])[t];
    ushort4 o; o.x = f2bf(v.x); o.y = f2bf(v.y); o.z = f2bf(v.z); o.w = f2bf(v.w);
    ((ushort4*)&VB[(long)r * 768])[t] = o;
}

// ---------------------------------------------------------------------------
// 2. X = [cls_embedding; token_reps], bf16
// ---------------------------------------------------------------------------
__global__ void build_x_kernel(const float* __restrict__ tok, const float* __restrict__ clsemb,
                               unsigned short* __restrict__ X){
    int r = blockIdx.x;
    int b = r / SP1, s = r % SP1;
    const float* src = (s == 0) ? clsemb : &tok[((long)b * S_ + (s - 1)) * H_];
    for (int d = threadIdx.x; d < H_; d += 256)
        X[(long)r * H_ + d] = f2bf(src[d]);
}

// ---------------------------------------------------------------------------
// 3. merged precompute: q (192 blk), BiasC (768 blk), WC (768 blk)
// ---------------------------------------------------------------------------
__global__ void precomp_kernel(const float* __restrict__ clsemb, const float* __restrict__ in_proj_w,
                               const float* __restrict__ in_proj_b, float* __restrict__ q,
                               const float* __restrict__ w1, const float* __restrict__ b1,
                               const float* __restrict__ opb, const float* __restrict__ cls_reps,
                               float* __restrict__ BiasC, const float* __restrict__ wtab,
                               float* __restrict__ WC){
    int blk = blockIdx.x;
    int wave = threadIdx.x >> 6, lane = threadIdx.x & 63;
    if (blk < 192){                                   // q projection
        int j = blk * 4 + wave;
        const float* wr = &in_proj_w[(long)j * H_];
        float p = 0.f;
        #pragma unroll
        for (int i = 0; i < 12; ++i) p += clsemb[lane + 64*i] * wr[lane + 64*i];
        p = wave_sum(p);
        if (lane == 0) q[j] = p + in_proj_b[j];
    } else if (blk < 192 + 768){                      // BiasC
        int i = (blk - 192) * 4 + wave;
        const float* row = &w1[(long)i * INDIM_];
        float p0 = 0.f, pb0 = 0.f, pb1 = 0.f, pb2 = 0.f, pb3 = 0.f;
        #pragma unroll
        for (int t = 0; t < 12; ++t){
            int k = lane + 64*t;
            p0 += opb[k] * row[k];
            float rv = row[832 + k];
            pb0 += cls_reps[0*H_ + k] * rv;
            pb1 += cls_reps[1*H_ + k] * rv;
            pb2 += cls_reps[2*H_ + k] * rv;
            pb3 += cls_reps[3*H_ + k] * rv;
        }
        p0 = wave_sum(p0); pb0 = wave_sum(pb0); pb1 = wave_sum(pb1);
        pb2 = wave_sum(pb2); pb3 = wave_sum(pb3);
        if (lane == 0){
            float base = b1[i] + p0;
            BiasC[0*INNER_ + i] = base + pb0;
            BiasC[1*INNER_ + i] = base + pb1;
            BiasC[2*INNER_ + i] = base + pb2;
            BiasC[3*INNER_ + i] = base + pb3;
        }
    } else {                                          // WC
        int i = (blk - 192 - 768) * 4 + wave;
        float rv = w1[(long)i * INDIM_ + 768 + lane];
        #pragma unroll
        for (int w = 0; w < 9; ++w){
            float p = wave_sum(wtab[w * WD_ + lane] * rv);
            if (lane == 0) WC[w * INNER_ + i] = p;
        }
    }
}

// ---------------------------------------------------------------------------
// 5. base scores
// ---------------------------------------------------------------------------
__global__ void scores_kernel(const float* __restrict__ q, const float* __restrict__ KV,
                              float* __restrict__ SC){
    int r = blockIdx.x;
    int h = threadIdx.x >> 6, lane = threadIdx.x & 63;
    const float* krow = &KV[(long)r * 1536 + h * DH_];
    const float* qh   = &q[h * DH_];
    float p = 0.f;
    #pragma unroll
    for (int i = 0; i < 3; ++i) p += qh[lane + 64*i] * krow[lane + 64*i];
    p = wave_sum(p);
    if (lane == 0){
        const float scale = 0.0721687836487032f;
        SC[((r / SP1) * NH_ + h) * SP1 + (r % SP1)] = p * scale;
    }
}

// ---------------------------------------------------------------------------
// 6. per-span attention (bf16 V, packed loads) -> CTX bf16
// ---------------------------------------------------------------------------
__global__ __launch_bounds__(192) void attn_kernel(
    const int* __restrict__ span_ids, const void* __restrict__ masks,
    const int* __restrict__ flag, const float* __restrict__ SC,
    const unsigned short* __restrict__ VB, unsigned short* __restrict__ CTX)
{
    int blk = blockIdx.x;
    int b = blk >> 12, n = blk & (N_ - 1);
    int t = threadIdx.x;
    __shared__ float w_sh[NH_][12];
    __shared__ int info[2];

    if (t == 0){
        long idx = (long)b * N_ + n;
        int start = span_ids[idx * 2 + 0];
        int end   = span_ids[idx * 2 + 1];
        bool sm = (*flag == 0) ? (((const unsigned*)masks)[idx] != 0u)
                               : (((const unsigned char*)masks)[idx] != 0);
        int cnt = sm ? (end - start) : 0;
        if (cnt < 0) cnt = 0;
        if (cnt > 8) cnt = 8;
        if (start < 0) start = 0;
        if (start + cnt > S_) cnt = S_ - start;
        info[0] = start; info[1] = cnt;
    }
    __syncthreads();
    int start = info[0], cnt = info[1];

    if (t < NH_){
        int h = t;
        const float* sc = &SC[((long)b * NH_ + h) * SP1];
        float m = sc[0];
        for (int j = 0; j < cnt; ++j) m = fmaxf(m, sc[1 + start + j]);
        float e0 = expf(sc[0] - m), sum = e0;
        float ej[8];
        for (int j = 0; j < cnt; ++j){ ej[j] = expf(sc[1 + start + j] - m); sum += ej[j]; }
        float inv = 1.f / sum;
        w_sh[h][0] = e0 * inv;
        for (int j = 0; j < cnt; ++j) w_sh[h][1 + j] = ej[j] * inv;
    }
    __syncthreads();

    long ctxbase = ((long)b * N_ + n) * H_;
    const unsigned short* V0 = VB + (long)(b * SP1) * 768;
    #pragma unroll
    for (int i = 0; i < 2; ++i){
        int p = t + 192 * i;           // ushort2 index 0..383
        int d = p * 2;
        int h = d / DH_;               // pairs never straddle heads (DH even)
        float w0 = w_sh[h][0];
        unsigned v = ((const unsigned*)V0)[p];
        float a0 = w0 * bf2f(v & 0xffffu), a1 = w0 * bf2f(v >> 16);
        for (int j = 0; j < cnt; ++j){
            unsigned vv = *(const unsigned*)(V0 + (long)(1 + start + j) * 768 + d);
            float wj = w_sh[h][1 + j];
            a0 += wj * bf2f(vv & 0xffffu);
            a1 += wj * bf2f(vv >> 16);
        }
        ((unsigned*)(CTX + ctxbase))[p] = (unsigned)f2bf(a0) | ((unsigned)f2bf(a1) << 16);
    }
}

// ---------------------------------------------------------------------------
// 7a. m97 128x128 GEMM (proven) — small GEMMs (KV, Wfuse)
// ---------------------------------------------------------------------------
template<int EPI>
__global__ __launch_bounds__(256, 2) void gemm97(
    const unsigned short* __restrict__ A, const unsigned short* __restrict__ Bm,
    const float* __restrict__ biasA, void* __restrict__ Cp,
    int M, int N, int K, int lda, int ldb, int ldc, int nbx)
{
    __shared__ unsigned short As[128 * 32];
    __shared__ unsigned short Bs[128 * 32];
    const int t = threadIdx.x, lane = t & 63, wave = t >> 6;
    const int wr = wave >> 1, wcid = wave & 1;

    int nwg = gridDim.x;
    int bid = blockIdx.x;
    int swz = ((nwg & 7) == 0) ? ((bid & 7) * (nwg >> 3) + (bid >> 3)) : bid;
    const int m0 = (swz / nbx) * 128;
    const int n0 = (swz % nbx) * 128;

    f32x4 acc[4][4];
    #pragma unroll
    for (int i = 0; i < 4; ++i)
        #pragma unroll
        for (int j = 0; j < 4; ++j)
            acc[i][j] = (f32x4){0.f, 0.f, 0.f, 0.f};

    const unsigned short* gA = A + (long)(m0 + wave*32 + (lane >> 2)) * lda + (lane & 3) * 8;
    const unsigned short* gB = Bm + (long)(n0 + wave*32 + (lane >> 2)) * ldb + (lane & 3) * 8;
    unsigned short* lA = &As[wave * 32 * 32];
    unsigned short* lB = &Bs[wave * 32 * 32];
    const long a16 = (long)16 * lda, b16 = (long)16 * ldb;

    for (int k0 = 0; k0 < K; k0 += 32){
        gld16(lA,       gA + k0);
        gld16(lA + 512, gA + a16 + k0);
        gld16(lB,       gB + k0);
        gld16(lB + 512, gB + b16 + k0);
        __syncthreads();

        bf16x8 af[4], bfr[4];
        #pragma unroll
        for (int f = 0; f < 4; ++f){
            af[f]  = *(const bf16x8*)&As[(wr*64 + f*16 + (lane & 15)) * 32 + (lane >> 4) * 8];
            bfr[f] = *(const bf16x8*)&Bs[(wcid*64 + f*16 + (lane & 15)) * 32 + (lane >> 4) * 8];
        }
        #pragma unroll
        for (int i = 0; i < 4; ++i)
            #pragma unroll
            for (int j = 0; j < 4; ++j)
                acc[i][j] = __builtin_amdgcn_mfma_f32_16x16x32_bf16(af[i], bfr[j], acc[i][j], 0, 0, 0);
        __syncthreads();
    }

    const int r0 = (lane >> 4) * 4;
    const int cc = lane & 15;
    #pragma unroll
    for (int i = 0; i < 4; ++i){
        int rowb = m0 + wr*64 + i*16 + r0;
        #pragma unroll
        for (int j = 0; j < 4; ++j){
            int col = n0 + wcid*64 + j*16 + cc;
            float cb = biasA ? biasA[col] : 0.f;
            #pragma unroll
            for (int r = 0; r < 4; ++r){
                long o = (long)(rowb + r) * ldc + col;
                float v = acc[i][j][r] + cb;
                if (EPI == 1) ((unsigned short*)Cp)[o] = f2bf(v);
                else          ((float*)Cp)[o] = v;
            }
        }
    }
}

// ---------------------------------------------------------------------------
// 7b. 256x256 GEMM v3: R3's proven 16x16 read layout + SINGLE barrier/phase
//     + counted vmcnt + T5 setprio + LDS-routed coalesced epilogue.
//     Units (2 gld16 each): U1=A rho0-127 (read P1), U2=B rho0-127 (P1),
//     U3=B rho128-255 (P2), U4=A rho128-255 (P3). Stage: U1'@P1, U2'@P2,
//     U3'@P3, U4'@P4. Waits (FIFO-derived): VMW(4)@P1,P2,P4; none @P3;
//     tail VMW(2)/VMW(0). Phase = {reads; stage; VMW; bar; MFMA}.
//     EPI: 0 = f32 out + col bias; 2 = bf16 out + relu + BiasC[4][N]+WC[9][N]
// ---------------------------------------------------------------------------
template<int EPI, int LDA_, int LDB_>
__global__ __launch_bounds__(512, 2) void gemm256v3(
    const unsigned short* __restrict__ A, const unsigned short* __restrict__ Bm,
    const float* __restrict__ biasA, const float* __restrict__ biasB,
    const int* __restrict__ widths, void* __restrict__ Cp,
    int K, int ldc, int nbx)
{
    __shared__ __align__(16) unsigned char lds[131072];
    const int t = threadIdx.x, lane = t & 63;
    const int wave = t >> 6;
    const int wr = wave >> 2, wc = wave & 3;      // 2M x 4N waves

    int nwg = gridDim.x, bid = blockIdx.x;
    int swz = ((nwg & 7) == 0) ? ((bid & 7) * (nwg >> 3) + (bid >> 3)) : bid;
    const int m0 = (swz / nbx) * 256;
    const int n0 = (swz % nbx) * 256;

    // staging (source pre-swizzled; LDS dest linear, wave-private 1KB slices)
    const int rQ = t >> 3;
    const int cswz = ((t & 7) ^ (rQ & 7)) << 3;
    const unsigned short* sA = A + (long)(m0 + rQ) * LDA_ + cswz;
    const unsigned short* sB = Bm + (long)(n0 + ((rQ >> 5) * 64 + (rQ & 31))) * LDB_ + cswz;
    const int wsl = wave * 1024;

    // ds_read bases (16x16 fragments — R3 proven conflict-free)
    const int aRow = (wr * 64 + (lane & 15)) * 128;
    const int bRow = (wc * 32 + (lane & 15)) * 128;
    const int pcl0 = (((lane >> 4) * 16)) ^ ((lane & 7) << 4);
    const int pcl1 = (64 + ((lane >> 4) * 16)) ^ ((lane & 7) << 4);

    f32x4 acc[8][4];
    #pragma unroll
    for (int i = 0; i < 8; ++i)
        #pragma unroll
        for (int j = 0; j < 4; ++j)
            acc[i][j] = (f32x4){0.f, 0.f, 0.f, 0.f};

    const int KT = K >> 6;

#define STG_(off, src) gld16((unsigned short*)(void*)(lds + (off) + wsl), (src))

    // prologue: FIFO order U1,U2,U3,U4
    STG_(0,             sA);
    STG_(8192,          sA + 128 * LDA_);
    STG_(65536,         sB);
    STG_(65536 + 8192,  sB + 128 * LDB_);
    STG_(65536 + 16384, sB + 32 * LDB_);
    STG_(65536 + 24576, sB + 160 * LDB_);
    STG_(16384,         sA + 64 * LDA_);
    STG_(24576,         sA + 192 * LDA_);
    VMW(4);
    wgbar();

    for (int kt = 0; kt < KT; ++kt){
        const unsigned rA = (unsigned)(kt & 1) * 32768u;
        const unsigned rB = 65536u + rA;
        const unsigned wA = (unsigned)((kt + 1) & 1) * 32768u;
        const unsigned wB = 65536u + wA;
        const unsigned short* pA = sA + (long)(kt + 1) * 64;
        const unsigned short* pB = sB + (long)(kt + 1) * 64;
        const bool more = (kt + 1 < KT);

        bf16x8 a0[4][2], bE[2][2], bO[2][2];

        // ===== P1: reads a0(U1)+bE(U2); stage U1'; VMW; bar; MFMA q(0,0)
        #pragma unroll
        for (int i = 0; i < 4; ++i){
            a0[i][0] = *(const bf16x8*)(lds + rA + aRow + i*2048 + pcl0);
            a0[i][1] = *(const bf16x8*)(lds + rA + aRow + i*2048 + pcl1);
        }
        #pragma unroll
        for (int j = 0; j < 2; ++j){
            bE[j][0] = *(const bf16x8*)(lds + rB + j*2048 + bRow + pcl0);
            bE[j][1] = *(const bf16x8*)(lds + rB + j*2048 + bRow + pcl1);
        }
        if (more){ STG_(wA, pA); STG_(wA + 8192, pA + 128 * LDA_); VMW(4); } else { VMW(2); }
        wgbar();
        __builtin_amdgcn_s_setprio(1);
        #pragma unroll
        for (int i = 0; i < 4; ++i)
            #pragma unroll
            for (int j = 0; j < 2; ++j){
                acc[i][j] = __builtin_amdgcn_mfma_f32_16x16x32_bf16(a0[i][0], bE[j][0], acc[i][j], 0, 0, 0);
                acc[i][j] = __builtin_amdgcn_mfma_f32_16x16x32_bf16(a0[i][1], bE[j][1], acc[i][j], 0, 0, 0);
            }
        __builtin_amdgcn_s_setprio(0);

        // ===== P2: reads bO(U3); stage U2'; VMW; bar; MFMA q(0,1)
        #pragma unroll
        for (int j = 0; j < 2; ++j){
            bO[j][0] = *(const bf16x8*)(lds + rB + 16384 + j*2048 + bRow + pcl0);
            bO[j][1] = *(const bf16x8*)(lds + rB + 16384 + j*2048 + bRow + pcl1);
        }
        if (more){ STG_(wB, pB); STG_(wB + 8192, pB + 128 * LDB_); VMW(4); } else { VMW(0); }
        wgbar();
        __builtin_amdgcn_s_setprio(1);
        #pragma unroll
        for (int i = 0; i < 4; ++i)
            #pragma unroll
            for (int j = 0; j < 2; ++j){
                acc[i][2+j] = __builtin_amdgcn_mfma_f32_16x16x32_bf16(a0[i][0], bO[j][0], acc[i][2+j], 0, 0, 0);
                acc[i][2+j] = __builtin_amdgcn_mfma_f32_16x16x32_bf16(a0[i][1], bO[j][1], acc[i][2+j], 0, 0, 0);
            }
        __builtin_amdgcn_s_setprio(0);

        // ===== P3: reads a1(U4); stage U3'; bar; MFMA q(1,0)   (no VMW)
        #pragma unroll
        for (int i = 0; i < 4; ++i){
            a0[i][0] = *(const bf16x8*)(lds + rA + 16384 + aRow + i*2048 + pcl0);
            a0[i][1] = *(const bf16x8*)(lds + rA + 16384 + aRow + i*2048 + pcl1);
        }
        if (more){ STG_(wB + 16384, pB + 32 * LDB_); STG_(wB + 24576, pB + 160 * LDB_); }
        wgbar();
        __builtin_amdgcn_s_setprio(1);
        #pragma unroll
        for (int i = 0; i < 4; ++i)
            #pragma unroll
            for (int j = 0; j < 2; ++j){
                acc[4+i][j] = __builtin_amdgcn_mfma_f32_16x16x32_bf16(a0[i][0], bE[j][0], acc[4+i][j], 0, 0, 0);
                acc[4+i][j] = __builtin_amdgcn_mfma_f32_16x16x32_bf16(a0[i][1], bE[j][1], acc[4+i][j], 0, 0, 0);
            }
        __builtin_amdgcn_s_setprio(0);

        // ===== P4: stage U4'; VMW; bar; MFMA q(1,1)
        if (more){
            STG_(wA + 16384, pA + 64 * LDA_);  STG_(wA + 24576, pA + 192 * LDA_);
            VMW(4);
        }
        wgbar();
        __builtin_amdgcn_s_setprio(1);
        #pragma unroll
        for (int i = 0; i < 4; ++i)
            #pragma unroll
            for (int j = 0; j < 2; ++j){
                acc[4+i][2+j] = __builtin_amdgcn_mfma_f32_16x16x32_bf16(a0[i][0], bO[j][0], acc[4+i][2+j], 0, 0, 0);
                acc[4+i][2+j] = __builtin_amdgcn_mfma_f32_16x16x32_bf16(a0[i][1], bO[j][1], acc[4+i][2+j], 0, 0, 0);
            }
        __builtin_amdgcn_s_setprio(0);
    }
#undef STG_

    // ---- epilogue via LDS (bijective XOR swizzle col^((row&7)<<4)), coalesced stores
    const int r0 = (lane >> 4) * 4;
    const int cc = lane & 15;
    const int Nn = nbx * 256;

    if (EPI == 2){
        const float* bcl = biasA + (long)(m0 >> 12) * Nn;
        wgbar();
        #pragma unroll
        for (int mq = 0; mq < 2; ++mq){
            #pragma unroll
            for (int i = 0; i < 4; ++i){
                #pragma unroll
                for (int r = 0; r < 4; ++r){
                    int row = mq*128 + wr*64 + i*16 + r0 + r;   // local 0..255
                    int wv = widths[m0 + row];
                    wv = (wv < 0) ? 0 : ((wv > 8) ? 8 : wv);
                    const float* wcb = biasB + (long)wv * Nn;
                    unsigned key = (unsigned)((row & 7) << 4);
                    unsigned rbase = (unsigned)row * 512u;
                    #pragma unroll
                    for (int j = 0; j < 4; ++j){
                        int col = wc*64 + j*16 + cc;            // local 0..255
                        float v = acc[4*mq + i][j][r] + bcl[n0 + col] + wcb[n0 + col];
                        v = fmaxf(v, 0.f);
                        *(unsigned short*)(lds + rbase + (((unsigned)col * 2u) ^ key)) = f2bf(v);
                    }
                }
            }
        }
        wgbar();
        #pragma unroll
        for (int k = 0; k < 16; ++k){
            int row = (t >> 5) + k*16;
            int l32 = t & 31;
            bf16x8 val = *(const bf16x8*)(lds + (unsigned)row*512u
                             + (((unsigned)l32*16u) ^ ((unsigned)(row & 7) << 4)));
            *(bf16x8*)((unsigned short*)Cp + (long)(m0 + row) * ldc + n0 + l32*8) = val;
        }
    } else {
        // f32 out: two half-tile passes through 128KB LDS
        #pragma unroll
        for (int h = 0; h < 2; ++h){
            wgbar();
            #pragma unroll
            for (int i = 0; i < 4; ++i){
                #pragma unroll
                for (int r = 0; r < 4; ++r){
                    int rloc = wr*64 + i*16 + r0 + r;           // 0..127
                    unsigned key = (unsigned)((rloc & 7) << 4);
                    unsigned rbase = (unsigned)rloc * 1024u;
                    #pragma unroll
                    for (int j = 0; j < 4; ++j){
                        int col = wc*64 + j*16 + cc;
                        float v = acc[4*h + i][j][r] + (biasA ? biasA[n0 + col] : 0.f);
                        *(float*)(lds + rbase + (((unsigned)col * 4u) ^ key)) = v;
                    }
                }
            }
            wgbar();
            #pragma unroll
            for (int k = 0; k < 16; ++k){
                int rloc = (t >> 6) + k*8;
                int l64 = t & 63;
                f32x4 val = *(const f32x4*)(lds + (unsigned)rloc*1024u
                                 + (((unsigned)l64*16u) ^ ((unsigned)(rloc & 7) << 4)));
                *(f32x4*)((float*)Cp + (long)(m0 + 128*h + rloc) * ldc + n0 + l64*4) = val;
            }
        }
    }
}

// ---------------------------------------------------------------------------
extern "C" void kernel_launch(void* const* d_in, const int* in_sizes, int n_in,
                              void* d_out, int out_size, void* d_ws, size_t ws_size,
                              hipStream_t stream)
{
    const float* token_reps  = (const float*)d_in[0];
    const int*   span_ids    = (const int*)d_in[1];
    const void*  span_masks  = d_in[2];
    const float* cls_reps    = (const float*)d_in[3];
    const int*   span_widths = (const int*)d_in[4];
    const float* cls_emb     = (const float*)d_in[5];
    const float* in_proj_w   = (const float*)d_in[6];
    const float* in_proj_b   = (const float*)d_in[7];
    const float* out_proj_w  = (const float*)d_in[8];
    const float* out_proj_b  = (const float*)d_in[9];
    const float* width_table = (const float*)d_in[10];
    const float* w1          = (const float*)d_in[11];
    const float* b1          = (const float*)d_in[12];
    const float* w2          = (const float*)d_in[13];
    const float* b2          = (const float*)d_in[14];

    char* ws = (char*)d_ws;
    size_t off = 0;
    auto alloc = [&](size_t bytes)->char*{
        char* p = ws + off;
        off += (bytes + 255) & ~(size_t)255;
        return p;
    };
    int*            flag  = (int*)           alloc(4);
    float*          qbuf  = (float*)         alloc((size_t)H_ * 4);
    unsigned short* Xb    = (unsigned short*)alloc((size_t)ROWS_XP * H_ * 2);
    unsigned short* Wkv   = (unsigned short*)alloc((size_t)1536 * H_ * 2);
    float*          KV    = (float*)         alloc((size_t)ROWS_XP * 1536 * 4);
    unsigned short* VB    = (unsigned short*)alloc((size_t)ROWS_X * 768 * 2);
    float*          SC    = (float*)         alloc((size_t)B_ * NH_ * SP1 * 4);
    unsigned short* CTX   = (unsigned short*)alloc((size_t)NSPAN * H_ * 2);
    unsigned short* W1a   = (unsigned short*)alloc((size_t)INNER_ * H_ * 2);
    unsigned short* OutT  = (unsigned short*)alloc((size_t)H_ * H_ * 2);
    unsigned short* Wfuse = (unsigned short*)alloc((size_t)INNER_ * H_ * 2);
    unsigned short* W2b   = (unsigned short*)alloc((size_t)H_ * INNER_ * 2);
    unsigned short* H1    = (unsigned short*)alloc((size_t)NSPAN * INNER_ * 2);
    float*          BiasC = (float*)         alloc((size_t)B_ * INNER_ * 4);
    float*          WC    = (float*)         alloc((size_t)9 * INNER_ * 4);
    (void)ws_size; (void)in_sizes; (void)n_in; (void)out_size;

    // prep / conversions
    detect_mask_kernel<<<1, 256, 0, stream>>>((const unsigned*)span_masks, flag);
    build_x_kernel<<<ROWS_X, 256, 0, stream>>>(token_reps, cls_emb, Xb);
    conv_f32_bf16<<<512, 256, 0, stream>>>(in_proj_w + (size_t)768 * H_, Wkv, (long)(1536 * H_ / 4));
    conv_f32_bf16<<<512, 256, 0, stream>>>(w2, W2b, (long)(H_ * INNER_ / 4));
    conv_w1a_kernel<<<INNER_, 192, 0, stream>>>(w1, W1a);
    transconv_kernel<<<dim3(24, 24), 256, 0, stream>>>(out_proj_w, OutT);
    precomp_kernel<<<192 + 768 + 768, 256, 0, stream>>>(
        cls_emb, in_proj_w, in_proj_b, qbuf,
        w1, b1, out_proj_b, cls_reps, BiasC, width_table, WC);

    // Wfused = W1a @ OutT^T   (3072x768, K=768)
    gemm97<1><<<(768/128) * (INNER_/128), 256, 0, stream>>>(
        W1a, OutT, nullptr, Wfuse, INNER_, 768, 768, 768, 768, 768, 768/128);

    // KV = X @ [wk;wv]^T + b   (2176x1536, K=768)
    gemm97<0><<<(1536/128) * (ROWS_XP/128), 256, 0, stream>>>(
        Xb, Wkv, in_proj_b + 768, KV, ROWS_XP, 1536, 768, 768, 768, 1536, 1536/128);

    vconv_kernel<<<ROWS_X, 192, 0, stream>>>(KV, VB);
    scores_kernel<<<ROWS_X, 256, 0, stream>>>(qbuf, KV, SC);
    attn_kernel<<<NSPAN, 192, 0, stream>>>(span_ids, span_masks, flag, SC, VB, CTX);

    // H1 = relu(CTX @ Wfused^T + BiasC[b] + WC[width])   (16384x3072, K=768)
    gemm256v3<2, 768, 768><<<(INNER_/256) * (NSPAN/256), 512, 0, stream>>>(
        CTX, Wfuse, BiasC, WC, span_widths, H1, 768, INNER_, INNER_/256);

    // out = H1 @ w2^T + b2   (16384x768, K=3072) -> f32 d_out
    gemm256v3<0, 3072, 3072><<<(768/256) * (NSPAN/256), 512, 0, stream>>>(
        H1, W2b, b2, nullptr, nullptr, (float*)d_out, 3072, 768, 768/256);
}

// Round 6
// 292.036 us; speedup vs baseline: 1.0854x; 1.0193x over previous
//
#include <hip/hip_runtime.h>
#include <hip/hip_bf16.h>
#include <math.h>

// Problem constants
#define B_      4
#define S_      512
#define H_      768
#define NH_     4
#define DH_     192
#define N_      4096          // spans per batch
#define WD_     64
#define INNER_  3072
#define INDIM_  1600
#define SP1     513           // S+1 (CLS prepended)
#define ROWS_X  (B_*SP1)      // 2052
#define ROWS_XP 2176          // padded to multiple of 128
#define NSPAN   (B_*N_)       // 16384

typedef __attribute__((ext_vector_type(8))) short bf16x8;
typedef __attribute__((ext_vector_type(4))) float f32x4;

__device__ __forceinline__ unsigned short f2bf(float f){
    unsigned u = __builtin_bit_cast(unsigned, f);
    u = u + 0x7FFFu + ((u >> 16) & 1u);   // round-to-nearest-even
    return (unsigned short)(u >> 16);
}
__device__ __forceinline__ float bf2f(unsigned hs){
    return __builtin_bit_cast(float, hs << 16);
}

__device__ __forceinline__ float wave_sum(float p){
    #pragma unroll
    for (int off = 32; off > 0; off >>= 1) p += __shfl_down(p, off);
    return p;
}

// async global->LDS, 16B per lane. lds must be wave-uniform; g is per-lane.
__device__ __forceinline__ void gld16(unsigned short* lds, const unsigned short* g){
    __builtin_amdgcn_global_load_lds(
        (const __attribute__((address_space(1))) unsigned int*)(const void*)g,
        (__attribute__((address_space(3))) unsigned int*)(void*)lds,
        16, 0, 0);
}

__device__ __forceinline__ void wgbar(){
    asm volatile("" ::: "memory");
    __builtin_amdgcn_s_barrier();
    asm volatile("" ::: "memory");
}
#define VMW(n) asm volatile("s_waitcnt vmcnt(" #n ")" ::: "memory")

// ---------------------------------------------------------------------------
// 1. mega prep kernel: all input conversions + precomputes in ONE launch.
//    block ranges: [0,1152) Wkv conv | [..,+2304) W2b conv | [+2052) build_x
//    | [+3072) w1a | [+576) transconv | [+192) q | [+768) BiasC | [+768) WC
//    | [+1) mask-detect.   All 256 threads.
// ---------------------------------------------------------------------------
__global__ __launch_bounds__(256) void mega_prep(
    const float* __restrict__ token_reps, const float* __restrict__ cls_emb,
    const float* __restrict__ in_proj_w, const float* __restrict__ in_proj_b,
    const float* __restrict__ out_proj_w, const float* __restrict__ out_proj_b,
    const float* __restrict__ cls_reps, const float* __restrict__ wtab,
    const float* __restrict__ w1, const float* __restrict__ b1,
    const float* __restrict__ w2, const unsigned* __restrict__ masks,
    unsigned short* __restrict__ Xb, unsigned short* __restrict__ Wkv,
    unsigned short* __restrict__ W2b, unsigned short* __restrict__ W1a,
    unsigned short* __restrict__ OutT, float* __restrict__ qbuf,
    float* __restrict__ BiasC, float* __restrict__ WC, int* __restrict__ flag)
{
    int b = blockIdx.x, t = threadIdx.x;
    __shared__ float tile[32][33];
    __shared__ int s_any;
    int wave = t >> 6, lane = t & 63;

    if (b < 1152){                                    // Wkv conversion
        long i = (long)b * 256 + t;                   // < 294912 f4
        float4 v = ((const float4*)(in_proj_w + (size_t)768 * H_))[i];
        ushort4 o; o.x = f2bf(v.x); o.y = f2bf(v.y); o.z = f2bf(v.z); o.w = f2bf(v.w);
        ((ushort4*)Wkv)[i] = o;
    } else if ((b -= 1152) < 2304){                   // W2b conversion
        long i = (long)b * 256 + t;                   // < 589824 f4
        float4 v = ((const float4*)w2)[i];
        ushort4 o; o.x = f2bf(v.x); o.y = f2bf(v.y); o.z = f2bf(v.z); o.w = f2bf(v.w);
        ((ushort4*)W2b)[i] = o;
    } else if ((b -= 2304) < 2052){                   // build X
        int r = b;
        int bb = r / SP1, s = r % SP1;
        const float* src = (s == 0) ? cls_emb : &token_reps[((long)bb * S_ + (s - 1)) * H_];
        for (int d = t; d < H_; d += 256)
            Xb[(long)r * H_ + d] = f2bf(src[d]);
    } else if ((b -= 2052) < 3072){                   // w1 cols [0,768) -> W1a
        if (t < 192){
            float4 v = ((const float4*)&w1[(long)b * INDIM_])[t];
            ushort4 o; o.x = f2bf(v.x); o.y = f2bf(v.y); o.z = f2bf(v.z); o.w = f2bf(v.w);
            ((ushort4*)&W1a[(long)b * 768])[t] = o;
        }
    } else if ((b -= 3072) < 576){                    // out_proj_w transpose-convert
        int bx = (b % 24) * 32, by = (b / 24) * 32;
        int tx = t & 31, ty = t >> 5;
        #pragma unroll
        for (int r = 0; r < 32; r += 8)
            tile[ty + r][tx] = out_proj_w[(long)(by + ty + r) * 768 + bx + tx];
        __syncthreads();
        #pragma unroll
        for (int r = 0; r < 32; r += 8)
            OutT[(long)(bx + ty + r) * 768 + by + tx] = f2bf(tile[tx][ty + r]);
    } else if ((b -= 576) < 192){                     // q projection
        int j = b * 4 + wave;
        const float* wr = &in_proj_w[(long)j * H_];
        float p = 0.f;
        #pragma unroll
        for (int i = 0; i < 12; ++i) p += cls_emb[lane + 64*i] * wr[lane + 64*i];
        p = wave_sum(p);
        if (lane == 0) qbuf[j] = p + in_proj_b[j];
    } else if ((b -= 192) < 768){                     // BiasC
        int i = b * 4 + wave;
        const float* row = &w1[(long)i * INDIM_];
        float p0 = 0.f, pb0 = 0.f, pb1 = 0.f, pb2 = 0.f, pb3 = 0.f;
        #pragma unroll
        for (int k0 = 0; k0 < 12; ++k0){
            int k = lane + 64*k0;
            p0 += out_proj_b[k] * row[k];
            float rv = row[832 + k];
            pb0 += cls_reps[0*H_ + k] * rv;
            pb1 += cls_reps[1*H_ + k] * rv;
            pb2 += cls_reps[2*H_ + k] * rv;
            pb3 += cls_reps[3*H_ + k] * rv;
        }
        p0 = wave_sum(p0); pb0 = wave_sum(pb0); pb1 = wave_sum(pb1);
        pb2 = wave_sum(pb2); pb3 = wave_sum(pb3);
        if (lane == 0){
            float base = b1[i] + p0;
            BiasC[0*INNER_ + i] = base + pb0;
            BiasC[1*INNER_ + i] = base + pb1;
            BiasC[2*INNER_ + i] = base + pb2;
            BiasC[3*INNER_ + i] = base + pb3;
        }
    } else if ((b -= 768) < 768){                     // WC
        int i = b * 4 + wave;
        float rv = w1[(long)i * INDIM_ + 768 + lane];
        #pragma unroll
        for (int w = 0; w < 9; ++w){
            float p = wave_sum(wtab[w * WD_ + lane] * rv);
            if (lane == 0) WC[w * INNER_ + i] = p;
        }
    } else {                                          // mask encoding detect
        if (t == 0) s_any = 0;
        __syncthreads();
        int any = 0;
        for (int i = t; i < 4096; i += 256){
            unsigned v = masks[i];
            if (!(v == 0u || v == 1u || v == 0x3F800000u)) any = 1;
        }
        if (any) s_any = 1;
        __syncthreads();
        if (t == 0) *flag = s_any;
    }
}

// ---------------------------------------------------------------------------
// 2. post-KV kernel: [0,2052) V->bf16  |  [2052,4104) base scores
// ---------------------------------------------------------------------------
__global__ __launch_bounds__(256) void post_kv_kernel(
    const float* __restrict__ KV, const float* __restrict__ q,
    unsigned short* __restrict__ VB, float* __restrict__ SC)
{
    int b = blockIdx.x, t = threadIdx.x;
    if (b < 2052){                                    // vconv
        if (t < 192){
            float4 v = ((const float4*)&KV[(long)b * 1536 + 768])[t];
            ushort4 o; o.x = f2bf(v.x); o.y = f2bf(v.y); o.z = f2bf(v.z); o.w = f2bf(v.w);
            ((ushort4*)&VB[(long)b * 768])[t] = o;
        }
    } else {                                          // scores
        int r = b - 2052;
        int h = t >> 6, lane = t & 63;
        const float* krow = &KV[(long)r * 1536 + h * DH_];
        const float* qh   = &q[h * DH_];
        float p = 0.f;
        #pragma unroll
        for (int i = 0; i < 3; ++i) p += qh[lane + 64*i] * krow[lane + 64*i];
        p = wave_sum(p);
        if (lane == 0){
            const float scale = 0.0721687836487032f;  // 1/sqrt(192)
            SC[((r / SP1) * NH_ + h) * SP1 + (r % SP1)] = p * scale;
        }
    }
}

// ---------------------------------------------------------------------------
// 3. per-span attention (bf16 V, packed loads) -> CTX bf16
// ---------------------------------------------------------------------------
__global__ __launch_bounds__(192) void attn_kernel(
    const int* __restrict__ span_ids, const void* __restrict__ masks,
    const int* __restrict__ flag, const float* __restrict__ SC,
    const unsigned short* __restrict__ VB, unsigned short* __restrict__ CTX)
{
    int blk = blockIdx.x;
    int b = blk >> 12, n = blk & (N_ - 1);
    int t = threadIdx.x;
    __shared__ float w_sh[NH_][12];
    __shared__ int info[2];

    if (t == 0){
        long idx = (long)b * N_ + n;
        int start = span_ids[idx * 2 + 0];
        int end   = span_ids[idx * 2 + 1];
        bool sm = (*flag == 0) ? (((const unsigned*)masks)[idx] != 0u)
                               : (((const unsigned char*)masks)[idx] != 0);
        int cnt = sm ? (end - start) : 0;
        if (cnt < 0) cnt = 0;
        if (cnt > 8) cnt = 8;
        if (start < 0) start = 0;
        if (start + cnt > S_) cnt = S_ - start;
        info[0] = start; info[1] = cnt;
    }
    __syncthreads();
    int start = info[0], cnt = info[1];

    if (t < NH_){
        int h = t;
        const float* sc = &SC[((long)b * NH_ + h) * SP1];
        float m = sc[0];
        for (int j = 0; j < cnt; ++j) m = fmaxf(m, sc[1 + start + j]);
        float e0 = expf(sc[0] - m), sum = e0;
        float ej[8];
        for (int j = 0; j < cnt; ++j){ ej[j] = expf(sc[1 + start + j] - m); sum += ej[j]; }
        float inv = 1.f / sum;
        w_sh[h][0] = e0 * inv;
        for (int j = 0; j < cnt; ++j) w_sh[h][1 + j] = ej[j] * inv;
    }
    __syncthreads();

    long ctxbase = ((long)b * N_ + n) * H_;
    const unsigned short* V0 = VB + (long)(b * SP1) * 768;
    #pragma unroll
    for (int i = 0; i < 2; ++i){
        int p = t + 192 * i;           // ushort2 index 0..383
        int d = p * 2;
        int h = d / DH_;
        float w0 = w_sh[h][0];
        unsigned v = ((const unsigned*)V0)[p];
        float a0 = w0 * bf2f(v & 0xffffu), a1 = w0 * bf2f(v >> 16);
        for (int j = 0; j < cnt; ++j){
            unsigned vv = *(const unsigned*)(V0 + (long)(1 + start + j) * 768 + d);
            float wj = w_sh[h][1 + j];
            a0 += wj * bf2f(vv & 0xffffu);
            a1 += wj * bf2f(vv >> 16);
        }
        ((unsigned*)(CTX + ctxbase))[p] = (unsigned)f2bf(a0) | ((unsigned)f2bf(a1) << 16);
    }
}

// ---------------------------------------------------------------------------
// 4. m97 128x128 GEMM (proven) — small GEMMs (KV, Wfuse)
// ---------------------------------------------------------------------------
template<int EPI>
__global__ __launch_bounds__(256, 2) void gemm97(
    const unsigned short* __restrict__ A, const unsigned short* __restrict__ Bm,
    const float* __restrict__ biasA, void* __restrict__ Cp,
    int M, int N, int K, int lda, int ldb, int ldc, int nbx)
{
    __shared__ unsigned short As[128 * 32];
    __shared__ unsigned short Bs[128 * 32];
    const int t = threadIdx.x, lane = t & 63, wave = t >> 6;
    const int wr = wave >> 1, wcid = wave & 1;

    int nwg = gridDim.x;
    int bid = blockIdx.x;
    int swz = ((nwg & 7) == 0) ? ((bid & 7) * (nwg >> 3) + (bid >> 3)) : bid;
    const int m0 = (swz / nbx) * 128;
    const int n0 = (swz % nbx) * 128;

    f32x4 acc[4][4];
    #pragma unroll
    for (int i = 0; i < 4; ++i)
        #pragma unroll
        for (int j = 0; j < 4; ++j)
            acc[i][j] = (f32x4){0.f, 0.f, 0.f, 0.f};

    const unsigned short* gA = A + (long)(m0 + wave*32 + (lane >> 2)) * lda + (lane & 3) * 8;
    const unsigned short* gB = Bm + (long)(n0 + wave*32 + (lane >> 2)) * ldb + (lane & 3) * 8;
    unsigned short* lA = &As[wave * 32 * 32];
    unsigned short* lB = &Bs[wave * 32 * 32];
    const long a16 = (long)16 * lda, b16 = (long)16 * ldb;

    for (int k0 = 0; k0 < K; k0 += 32){
        gld16(lA,       gA + k0);
        gld16(lA + 512, gA + a16 + k0);
        gld16(lB,       gB + k0);
        gld16(lB + 512, gB + b16 + k0);
        __syncthreads();

        bf16x8 af[4], bfr[4];
        #pragma unroll
        for (int f = 0; f < 4; ++f){
            af[f]  = *(const bf16x8*)&As[(wr*64 + f*16 + (lane & 15)) * 32 + (lane >> 4) * 8];
            bfr[f] = *(const bf16x8*)&Bs[(wcid*64 + f*16 + (lane & 15)) * 32 + (lane >> 4) * 8];
        }
        #pragma unroll
        for (int i = 0; i < 4; ++i)
            #pragma unroll
            for (int j = 0; j < 4; ++j)
                acc[i][j] = __builtin_amdgcn_mfma_f32_16x16x32_bf16(af[i], bfr[j], acc[i][j], 0, 0, 0);
        __syncthreads();
    }

    const int r0 = (lane >> 4) * 4;
    const int cc = lane & 15;
    #pragma unroll
    for (int i = 0; i < 4; ++i){
        int rowb = m0 + wr*64 + i*16 + r0;
        #pragma unroll
        for (int j = 0; j < 4; ++j){
            int col = n0 + wcid*64 + j*16 + cc;
            float cb = biasA ? biasA[col] : 0.f;
            #pragma unroll
            for (int r = 0; r < 4; ++r){
                long o = (long)(rowb + r) * ldc + col;
                float v = acc[i][j][r] + cb;
                if (EPI == 1) ((unsigned short*)Cp)[o] = f2bf(v);
                else          ((float*)Cp)[o] = v;
            }
        }
    }
}

// ---------------------------------------------------------------------------
// 5. 256x256 GEMM v4: one-phase-ahead operand prefetch.
//    Phase = {VMW; stage; bar; prefetch-reads (post-barrier = cross-wave safe);
//    setprio MFMA}.  Every MFMA cluster's operands were ds_read >=1 phase
//    earlier -> lgkmcnt stall ~0, LDS-pipe read burst overlaps matrix pipe.
//    Units (2 gld16 each): U1=A-lo (rows wr*128+[0,64)), U2=B-even,
//    U3=B-odd, U4=A-hi (rows wr*128+[64,128)).
//    Stage: U1'@P1, U2'@P2, U3'@P3, U4'@P4.  FIFO (VMW before stage):
//    VMW(2)@P1 drains U3'; VMW(2)@P2 drains U4'; VMW(2)@P4 drains U1',U2'.
//    Reads: P1: aL[2,3](kt)+bO(kt) | P2: aH[0,1](kt) | P3: aH[2,3](kt)
//           P4: aL[0,1](kt+1)+bE(kt+1).   Tail: VMW(2)/VMW(0).
//    Epilogue row map (FIXED from R5): row = wr*128 + mq*64 + i*16 + r0 + r.
//    EPI: 0 = f32 out + col bias; 2 = bf16 out + relu + BiasC[4][N]+WC[9][N]
// ---------------------------------------------------------------------------
template<int EPI, int LDA_, int LDB_>
__global__ __launch_bounds__(512, 2) void gemm256v4(
    const unsigned short* __restrict__ A, const unsigned short* __restrict__ Bm,
    const float* __restrict__ biasA, const float* __restrict__ biasB,
    const int* __restrict__ widths, void* __restrict__ Cp,
    int K, int ldc, int nbx)
{
    __shared__ __align__(16) unsigned char lds[131072];
    const int t = threadIdx.x, lane = t & 63;
    const int wave = t >> 6;
    const int wr = wave >> 2, wc = wave & 3;      // 2M x 4N waves

    int nwg = gridDim.x, bid = blockIdx.x;
    int swz = ((nwg & 7) == 0) ? ((bid & 7) * (nwg >> 3) + (bid >> 3)) : bid;
    const int m0 = (swz / nbx) * 256;
    const int n0 = (swz % nbx) * 256;

    // staging (source pre-swizzled; LDS dest linear, wave-private 1KB slices)
    const int rQ = t >> 3;
    const int cswz = ((t & 7) ^ (rQ & 7)) << 3;
    const unsigned short* sA = A + (long)(m0 + rQ) * LDA_ + cswz;
    const unsigned short* sB = Bm + (long)(n0 + ((rQ >> 5) * 64 + (rQ & 31))) * LDB_ + cswz;
    const int wsl = wave * 1024;

    // ds_read bases (16x16 fragments, conflict-free swizzle)
    const int aRow = (wr * 64 + (lane & 15)) * 128;
    const int bRow = (wc * 32 + (lane & 15)) * 128;
    const int pcl0 = (((lane >> 4) * 16)) ^ ((lane & 7) << 4);
    const int pcl1 = (64 + ((lane >> 4) * 16)) ^ ((lane & 7) << 4);

    f32x4 acc[8][4];
    #pragma unroll
    for (int i = 0; i < 8; ++i)
        #pragma unroll
        for (int j = 0; j < 4; ++j)
            acc[i][j] = (f32x4){0.f, 0.f, 0.f, 0.f};

    const int KT = K >> 6;
    bf16x8 aL[4][2], aH[4][2], bE[2][2], bO[2][2];

#define STG_(off, src) gld16((unsigned short*)(void*)(lds + (off) + wsl), (src))
#define RD_AL(fi, base) { aL[fi][0] = *(const bf16x8*)(lds + (base) + aRow + (fi)*2048 + pcl0); \
                          aL[fi][1] = *(const bf16x8*)(lds + (base) + aRow + (fi)*2048 + pcl1); }
#define RD_AH(fi, base) { aH[fi][0] = *(const bf16x8*)(lds + (base) + 16384 + aRow + (fi)*2048 + pcl0); \
                          aH[fi][1] = *(const bf16x8*)(lds + (base) + 16384 + aRow + (fi)*2048 + pcl1); }
#define RD_BE(jj, base) { bE[jj][0] = *(const bf16x8*)(lds + (base) + (jj)*2048 + bRow + pcl0); \
                          bE[jj][1] = *(const bf16x8*)(lds + (base) + (jj)*2048 + bRow + pcl1); }
#define RD_BO(jj, base) { bO[jj][0] = *(const bf16x8*)(lds + (base) + 16384 + (jj)*2048 + bRow + pcl0); \
                          bO[jj][1] = *(const bf16x8*)(lds + (base) + 16384 + (jj)*2048 + bRow + pcl1); }
#define Q_MFMA(AR, BR, I0, J0) \
    __builtin_amdgcn_s_setprio(1); \
    _Pragma("unroll") \
    for (int i = 0; i < 4; ++i) \
        _Pragma("unroll") \
        for (int j = 0; j < 2; ++j){ \
            acc[(I0)+i][(J0)+j] = __builtin_amdgcn_mfma_f32_16x16x32_bf16(AR[i][0], BR[j][0], acc[(I0)+i][(J0)+j], 0, 0, 0); \
            acc[(I0)+i][(J0)+j] = __builtin_amdgcn_mfma_f32_16x16x32_bf16(AR[i][1], BR[j][1], acc[(I0)+i][(J0)+j], 0, 0, 0); \
        } \
    __builtin_amdgcn_s_setprio(0);

    // ---- prologue: stage K-tile 0 (FIFO U1,U2,U3,U4); read aL[0,1], bE ----
    STG_(0,             sA);
    STG_(8192,          sA + 128 * LDA_);
    STG_(65536,         sB);
    STG_(65536 + 8192,  sB + 128 * LDB_);
    STG_(65536 + 16384, sB + 32 * LDB_);
    STG_(65536 + 24576, sB + 160 * LDB_);
    STG_(16384,         sA + 64 * LDA_);
    STG_(24576,         sA + 192 * LDA_);
    VMW(4);                                   // U1,U2 landed (all waves pre-bar)
    wgbar();
    RD_AL(0, 0u); RD_AL(1, 0u);
    RD_BE(0, 65536u); RD_BE(1, 65536u);

    // ---- main loop: kt = 0 .. KT-2 ----
    for (int kt = 0; kt < KT - 1; ++kt){
        const unsigned rA = (unsigned)(kt & 1) * 32768u;
        const unsigned rB = 65536u + rA;
        const unsigned wA = rA ^ 32768u;
        const unsigned wB = 65536u + wA;
        const unsigned short* pA = sA + (long)(kt + 1) * 64;
        const unsigned short* pB = sB + (long)(kt + 1) * 64;

        // ===== P1: drain U3'; stage U1'; bar; read aL[2,3]+bO; MFMA q00
        VMW(2);
        STG_(wA, pA); STG_(wA + 8192, pA + 128 * LDA_);
        wgbar();
        RD_AL(2, rA); RD_AL(3, rA);
        RD_BO(0, rB); RD_BO(1, rB);
        Q_MFMA(aL, bE, 0, 0);

        // ===== P2: drain U4'; stage U2'; bar; read aH[0,1]; MFMA q01
        VMW(2);
        STG_(wB, pB); STG_(wB + 8192, pB + 128 * LDB_);
        wgbar();
        RD_AH(0, rA); RD_AH(1, rA);
        Q_MFMA(aL, bO, 0, 2);

        // ===== P3: stage U3'; bar; read aH[2,3]; MFMA q10
        STG_(wB + 16384, pB + 32 * LDB_); STG_(wB + 24576, pB + 160 * LDB_);
        wgbar();
        RD_AH(2, rA); RD_AH(3, rA);
        Q_MFMA(aH, bE, 4, 0);

        // ===== P4: drain U1',U2'; stage U4'; bar; read aL[0,1]'+bE' (kt+1); MFMA q11
        VMW(2);
        STG_(wA + 16384, pA + 64 * LDA_); STG_(wA + 24576, pA + 192 * LDA_);
        wgbar();
        RD_AL(0, wA); RD_AL(1, wA);
        RD_BE(0, wB); RD_BE(1, wB);
        Q_MFMA(aH, bO, 4, 2);
    }

    // ---- tail: kt = KT-1 ----
    {
        const unsigned rA = (unsigned)((KT - 1) & 1) * 32768u;
        const unsigned rB = 65536u + rA;
        VMW(2);                               // drain U3 (last tile)
        wgbar();
        RD_AL(2, rA); RD_AL(3, rA);
        RD_BO(0, rB); RD_BO(1, rB);
        Q_MFMA(aL, bE, 0, 0);
        VMW(0);                               // drain U4
        wgbar();
        RD_AH(0, rA); RD_AH(1, rA);
        Q_MFMA(aL, bO, 0, 2);
        RD_AH(2, rA); RD_AH(3, rA);
        Q_MFMA(aH, bE, 4, 0);
        Q_MFMA(aH, bO, 4, 2);
    }
#undef STG_
#undef RD_AL
#undef RD_AH
#undef RD_BE
#undef RD_BO
#undef Q_MFMA

    // ---- epilogue via LDS routing; FIXED row map: wr*128 + mq*64 + i*16 + ...
    const int r0 = (lane >> 4) * 4;
    const int cc = lane & 15;
    const int Nn = nbx * 256;

    if (EPI == 2){
        const float* bcl = biasA + (long)(m0 >> 12) * Nn;
        wgbar();
        #pragma unroll
        for (int mq = 0; mq < 2; ++mq){
            #pragma unroll
            for (int i = 0; i < 4; ++i){
                #pragma unroll
                for (int r = 0; r < 4; ++r){
                    int row = wr*128 + mq*64 + i*16 + r0 + r;   // local 0..255
                    int wv = widths[m0 + row];
                    wv = (wv < 0) ? 0 : ((wv > 8) ? 8 : wv);
                    const float* wcb = biasB + (long)wv * Nn;
                    unsigned key = (unsigned)((row & 7) << 4);
                    unsigned rbase = (unsigned)row * 512u;
                    #pragma unroll
                    for (int j = 0; j < 4; ++j){
                        int col = wc*64 + j*16 + cc;            // local 0..255
                        float v = acc[4*mq + i][j][r] + bcl[n0 + col] + wcb[n0 + col];
                        v = fmaxf(v, 0.f);
                        *(unsigned short*)(lds + rbase + (((unsigned)col * 2u) ^ key)) = f2bf(v);
                    }
                }
            }
        }
        wgbar();
        #pragma unroll
        for (int k = 0; k < 16; ++k){
            int row = (t >> 5) + k*16;
            int l32 = t & 31;
            bf16x8 val = *(const bf16x8*)(lds + (unsigned)row*512u
                             + (((unsigned)l32*16u) ^ ((unsigned)(row & 7) << 4)));
            *(bf16x8*)((unsigned short*)Cp + (long)(m0 + row) * ldc + n0 + l32*8) = val;
        }
    } else {
        // f32 out: two half-tile passes; pass h holds storage rows h*128+[0,128)
        // which belong to waves with wr == h (rows wr*128 + mq*64 + ...).
        #pragma unroll
        for (int h = 0; h < 2; ++h){
            wgbar();
            if (wr == h){
                #pragma unroll
                for (int mq = 0; mq < 2; ++mq){
                    #pragma unroll
                    for (int i = 0; i < 4; ++i){
                        #pragma unroll
                        for (int r = 0; r < 4; ++r){
                            int rloc = mq*64 + i*16 + r0 + r;   // 0..127
                            unsigned key = (unsigned)((rloc & 7) << 4);
                            unsigned rbase = (unsigned)rloc * 1024u;
                            #pragma unroll
                            for (int j = 0; j < 4; ++j){
                                int col = wc*64 + j*16 + cc;
                                float v = acc[4*mq + i][j][r] + (biasA ? biasA[n0 + col] : 0.f);
                                *(float*)(lds + rbase + (((unsigned)col * 4u) ^ key)) = v;
                            }
                        }
                    }
                }
            }
            wgbar();
            #pragma unroll
            for (int k = 0; k < 16; ++k){
                int rloc = (t >> 6) + k*8;
                int l64 = t & 63;
                f32x4 val = *(const f32x4*)(lds + (unsigned)rloc*1024u
                                 + (((unsigned)l64*16u) ^ ((unsigned)(rloc & 7) << 4)));
                *(f32x4*)((float*)Cp + (long)(m0 + 128*h + rloc) * ldc + n0 + l64*4) = val;
            }
        }
    }
}

// ---------------------------------------------------------------------------
extern "C" void kernel_launch(void* const* d_in, const int* in_sizes, int n_in,
                              void* d_out, int out_size, void* d_ws, size_t ws_size,
                              hipStream_t stream)
{
    const float* token_reps  = (const float*)d_in[0];
    const int*   span_ids    = (const int*)d_in[1];
    const void*  span_masks  = d_in[2];
    const float* cls_reps    = (const float*)d_in[3];
    const int*   span_widths = (const int*)d_in[4];
    const float* cls_emb     = (const float*)d_in[5];
    const float* in_proj_w   = (const float*)d_in[6];
    const float* in_proj_b   = (const float*)d_in[7];
    const float* out_proj_w  = (const float*)d_in[8];
    const float* out_proj_b  = (const float*)d_in[9];
    const float* width_table = (const float*)d_in[10];
    const float* w1          = (const float*)d_in[11];
    const float* b1          = (const float*)d_in[12];
    const float* w2          = (const float*)d_in[13];
    const float* b2          = (const float*)d_in[14];

    char* ws = (char*)d_ws;
    size_t off = 0;
    auto alloc = [&](size_t bytes)->char*{
        char* p = ws + off;
        off += (bytes + 255) & ~(size_t)255;
        return p;
    };
    int*            flag  = (int*)           alloc(4);
    float*          qbuf  = (float*)         alloc((size_t)H_ * 4);
    unsigned short* Xb    = (unsigned short*)alloc((size_t)ROWS_XP * H_ * 2);
    unsigned short* Wkv   = (unsigned short*)alloc((size_t)1536 * H_ * 2);
    float*          KV    = (float*)         alloc((size_t)ROWS_XP * 1536 * 4);
    unsigned short* VB    = (unsigned short*)alloc((size_t)ROWS_X * 768 * 2);
    float*          SC    = (float*)         alloc((size_t)B_ * NH_ * SP1 * 4);
    unsigned short* CTX   = (unsigned short*)alloc((size_t)NSPAN * H_ * 2);
    unsigned short* W1a   = (unsigned short*)alloc((size_t)INNER_ * H_ * 2);
    unsigned short* OutT  = (unsigned short*)alloc((size_t)H_ * H_ * 2);
    unsigned short* Wfuse = (unsigned short*)alloc((size_t)INNER_ * H_ * 2);
    unsigned short* W2b   = (unsigned short*)alloc((size_t)H_ * INNER_ * 2);
    unsigned short* H1    = (unsigned short*)alloc((size_t)NSPAN * INNER_ * 2);
    float*          BiasC = (float*)         alloc((size_t)B_ * INNER_ * 4);
    float*          WC    = (float*)         alloc((size_t)9 * INNER_ * 4);
    (void)ws_size; (void)in_sizes; (void)n_in; (void)out_size;

    // all conversions + precomputes in one launch
    mega_prep<<<10885, 256, 0, stream>>>(
        token_reps, cls_emb, in_proj_w, in_proj_b, out_proj_w, out_proj_b,
        cls_reps, width_table, w1, b1, w2, (const unsigned*)span_masks,
        Xb, Wkv, W2b, W1a, OutT, qbuf, BiasC, WC, flag);

    // Wfused = W1a @ OutT^T   (3072x768, K=768)
    gemm97<1><<<(768/128) * (INNER_/128), 256, 0, stream>>>(
        W1a, OutT, nullptr, Wfuse, INNER_, 768, 768, 768, 768, 768, 768/128);

    // KV = X @ [wk;wv]^T + b   (2176x1536, K=768)
    gemm97<0><<<(1536/128) * (ROWS_XP/128), 256, 0, stream>>>(
        Xb, Wkv, in_proj_b + 768, KV, ROWS_XP, 1536, 768, 768, 768, 1536, 1536/128);

    // V->bf16 + base scores
    post_kv_kernel<<<2052 + 2052, 256, 0, stream>>>(KV, qbuf, VB, SC);

    attn_kernel<<<NSPAN, 192, 0, stream>>>(span_ids, span_masks, flag, SC, VB, CTX);

    // H1 = relu(CTX @ Wfused^T + BiasC[b] + WC[width])   (16384x3072, K=768)
    gemm256v4<2, 768, 768><<<(INNER_/256) * (NSPAN/256), 512, 0, stream>>>(
        CTX, Wfuse, BiasC, WC, span_widths, H1, 768, INNER_, INNER_/256);

    // out = H1 @ w2^T + b2   (16384x768, K=3072) -> f32 d_out
    gemm256v4<0, 3072, 3072><<<(768/256) * (NSPAN/256), 512, 0, stream>>>(
        H1, W2b, b2, nullptr, nullptr, (float*)d_out, 3072, 768, 768/256);
}